// Round 8
// baseline (75.611 us; speedup 1.0000x reference)
//
#include <hip/hip_runtime.h>
#include <hip/hip_bf16.h>
#include <cstddef>

#define NAGENT 8
#define DIN    128
#define HID    64
#define NACT   16

typedef __attribute__((ext_vector_type(8))) short bf16x8;
typedef __attribute__((ext_vector_type(4))) float f32x4;

__device__ __forceinline__ short f2bf(float f) {
    __hip_bfloat16 h = __float2bfloat16(f);      // RNE; pairs pack to v_cvt_pk_bf16_f32
    union { __hip_bfloat16 h; short s; } u; u.h = h;
    return u.s;
}
__device__ __forceinline__ float sigmoid_f(float v) { return 1.0f / (1.0f + __expf(-v)); }
__device__ __forceinline__ float tanh_f(float v) {
    v = fminf(fmaxf(v, -15.0f), 15.0f);
    float e = __expf(2.0f * v);
    return (e - 1.0f) / (e + 1.0f);
}
__device__ __forceinline__ bf16x8 cvt8pair(float4 v0, float4 v1) {
    bf16x8 r;
    r[0] = f2bf(v0.x); r[1] = f2bf(v0.y); r[2] = f2bf(v0.z); r[3] = f2bf(v0.w);
    r[4] = f2bf(v1.x); r[5] = f2bf(v1.y); r[6] = f2bf(v1.z); r[7] = f2bf(v1.w);
    return r;
}

// ---------------- weight fp32 -> bf16 fragment-major packing ----------------
// Per-agent packed layout (shorts), base a*33792:
//   W1  chunks c in [0,1024):    c = (n*4+k)*64 + lane      -> W1[a][n*16+lr][k*32+lk*8 ..+8]
//   Wih chunks c in [1024,2560): c-1024 = ((g*4+n)*2+kk)*64+lane -> Wih[a][g*64+n*16+lr][kk*32+lk*8..]
//   Whh chunks c in [2560,4096): same with Whh
//   W2  chunks c in [4096,4224): c-4096 = kk*64+lane        -> W2[a][lr][kk*32+lk*8..]
extern "C" __global__ void __launch_bounds__(256)
conv_weights_packed(const float* __restrict__ W1, const float* __restrict__ Wih,
                    const float* __restrict__ Whh, const float* __restrict__ W2,
                    short* __restrict__ ws)
{
    const int a = blockIdx.y;
    const int c = blockIdx.x * 256 + threadIdx.x;
    if (c >= 4224) return;
    const int lane = c & 63, lr = lane & 15, lk = lane >> 4;
    const float* src;
    if (c < 1024) {
        int n = c >> 8, k = (c >> 6) & 3;
        src = W1 + a * 8192 + (n * 16 + lr) * 128 + k * 32 + lk * 8;
    } else if (c < 2560) {
        int idx = (c - 1024) >> 6;
        int g = idx >> 3, n = (idx >> 1) & 3, kk = idx & 1;
        src = Wih + a * 12288 + (g * 64 + n * 16 + lr) * 64 + kk * 32 + lk * 8;
    } else if (c < 4096) {
        int idx = (c - 2560) >> 6;
        int g = idx >> 3, n = (idx >> 1) & 3, kk = idx & 1;
        src = Whh + a * 12288 + (g * 64 + n * 16 + lr) * 64 + kk * 32 + lk * 8;
    } else {
        int kk = (c - 4096) >> 6;
        src = W2 + a * 1024 + lr * 64 + kk * 32 + lk * 8;
    }
    float4 v0 = ((const float4*)src)[0];
    float4 v1 = ((const float4*)src)[1];
    bf16x8 o = cvt8pair(v0, v1);
    *(bf16x8*)(ws + (size_t)a * 33792 + (size_t)c * 8) = o;
}

// ---------------- main fused kernel ----------------
// grid (B/64, A) = 2048 blocks, 256 threads (4 waves), ONE 16-row tile per
// wave. No weight LDS staging, no barriers: all weight fragments stream from
// the packed d_ws buffer as contiguous 1KB wave bursts (528KB total, L2-
// resident per XCD). LDS = 4 x 2KB per-wave transpose buffers only.
// Register discipline (the r4-r7 lesson): no prefetch arrays, per-gate
// accumulator scoping, hp loads issued after gate 0 (L1 hits), biases loaded
// per tile (L2 hits). Target: fit the 128-VGPR cap with ZERO spill ->
// 4 blocks/CU = 16 waves/CU = 4 waves/SIMD.
extern "C" __global__ void __launch_bounds__(256, 4)
rnn_main(const float* __restrict__ x,     // [B*A, D]
         const float* __restrict__ hin,   // [B, A, H]
         const float* __restrict__ b1, const float* __restrict__ bih,
         const float* __restrict__ bhh, const float* __restrict__ b2,
         const short* __restrict__ wsp,   // packed bf16 weights
         float* __restrict__ qout,        // [B*A, NACT]
         float* __restrict__ hout)        // [B, A, H]
{
    const int a    = blockIdx.y;
    const int t    = threadIdx.x;
    const int wid  = t >> 6;              // 0..3
    const int lane = t & 63;
    const int lr   = lane & 15;
    const int lk   = lane >> 4;

    __shared__ short zs[4 * 1024];        // 4 per-wave 2KB transpose buffers
    char* zb = (char*)(zs + wid * 1024);

    const short* wsA = wsp + (size_t)a * 33792;
    const int tile = blockIdx.x * 4 + wid;
    const int arow = tile * 16 + lr;

    // ---- x / h rows -> bf16 fragments (the only cold HBM loads) ----
    const float* xrow = x + ((size_t)arow * NAGENT + a) * DIN + lk * 8;
    const float* hrow = hin + ((size_t)arow * NAGENT + a) * HID + lk * 8;
    bf16x8 xf[4], hf[2];
    #pragma unroll
    for (int k = 0; k < 4; ++k)
        xf[k] = cvt8pair(*(const float4*)(xrow + k * 32),
                         *(const float4*)(xrow + k * 32 + 4));
    #pragma unroll
    for (int kk = 0; kk < 2; ++kk)
        hf[kk] = cvt8pair(*(const float4*)(hrow + kk * 32),
                          *(const float4*)(hrow + kk * 32 + 4));

    // ---- fc1: z1 = relu(x @ W1^T + b1) ----
    {
        f32x4 acc1[4];
        #pragma unroll
        for (int n = 0; n < 4; ++n) {
            float bv = b1[a * HID + n * 16 + lr];
            acc1[n] = (f32x4){bv, bv, bv, bv};
        }
        #pragma unroll
        for (int k = 0; k < 4; ++k)
            #pragma unroll
            for (int n = 0; n < 4; ++n) {
                bf16x8 wb = *(const bf16x8*)(wsA + ((n * 4 + k) * 64 + lane) * 8);
                acc1[n] = __builtin_amdgcn_mfma_f32_16x16x32_bf16(xf[k], wb, acc1[n], 0, 0, 0);
            }
        #pragma unroll
        for (int n = 0; n < 4; ++n)
            #pragma unroll
            for (int j = 0; j < 4; ++j) {
                int row = lk * 4 + j, col = n * 16 + lr;
                *(short*)(zb + row * 128 + ((col * 2) ^ ((row & 7) << 4))) =
                    f2bf(fmaxf(acc1[n][j], 0.0f));
            }
    }

    // ---- z1 back as A-fragments (LDS round trip covered by gate-0 h-MFMAs) ----
    bf16x8 za0 = *(const bf16x8*)(zb + lr * 128 + ((0 * 64 + lk * 16) ^ ((lr & 7) << 4)));
    bf16x8 za1 = *(const bf16x8*)(zb + lr * 128 + ((1 * 64 + lk * 16) ^ ((lr & 7) << 4)));

    float rg[16], zg[16];
    float hp[16];

    #pragma unroll
    for (int g = 0; g < 3; ++g) {
        // h-path accumulators for THIS gate only (16 floats live)
        f32x4 aH[4];
        #pragma unroll
        for (int n = 0; n < 4; ++n) {
            float bh = bhh[a * 3 * HID + g * HID + n * 16 + lr];
            aH[n] = (f32x4){bh, bh, bh, bh};
        }
        #pragma unroll
        for (int kk = 0; kk < 2; ++kk)
            #pragma unroll
            for (int n = 0; n < 4; ++n) {
                bf16x8 wh = *(const bf16x8*)(wsA + 20480 +
                              (((g * 4 + n) * 2 + kk) * 64 + lane) * 8);
                aH[n] = __builtin_amdgcn_mfma_f32_16x16x32_bf16(hf[kk], wh, aH[n], 0, 0, 0);
            }

        f32x4 aI[4];
        #pragma unroll
        for (int n = 0; n < 4; ++n) {
            float bi = bih[a * 3 * HID + g * HID + n * 16 + lr];
            aI[n] = (f32x4){bi, bi, bi, bi};
        }
        #pragma unroll
        for (int n = 0; n < 4; ++n) {
            bf16x8 wi0 = *(const bf16x8*)(wsA + 8192 +
                          (((g * 4 + n) * 2 + 0) * 64 + lane) * 8);
            bf16x8 wi1 = *(const bf16x8*)(wsA + 8192 +
                          (((g * 4 + n) * 2 + 1) * 64 + lane) * 8);
            aI[n] = __builtin_amdgcn_mfma_f32_16x16x32_bf16(za0, wi0, aI[n], 0, 0, 0);
            aI[n] = __builtin_amdgcn_mfma_f32_16x16x32_bf16(za1, wi1, aI[n], 0, 0, 0);
        }

        if (g == 0) {
            #pragma unroll
            for (int n = 0; n < 4; ++n)
                #pragma unroll
                for (int j = 0; j < 4; ++j)
                    rg[n * 4 + j] = sigmoid_f(aI[n][j] + aH[n][j]);
            // issue hp loads now: L1 hits (same lines as hrow), consumed in g==2
            #pragma unroll
            for (int n = 0; n < 4; ++n)
                #pragma unroll
                for (int j = 0; j < 4; ++j)
                    hp[n * 4 + j] =
                        hin[((size_t)(tile * 16 + lk * 4 + j) * NAGENT + a) * HID + n * 16 + lr];
        } else if (g == 1) {
            #pragma unroll
            for (int n = 0; n < 4; ++n)
                #pragma unroll
                for (int j = 0; j < 4; ++j)
                    zg[n * 4 + j] = sigmoid_f(aI[n][j] + aH[n][j]);
        } else {
            #pragma unroll
            for (int n = 0; n < 4; ++n)
                #pragma unroll
                for (int j = 0; j < 4; ++j) {
                    int row = lk * 4 + j, col = n * 16 + lr;
                    float nn = tanh_f(aI[n][j] + rg[n * 4 + j] * aH[n][j]);
                    float zv = zg[n * 4 + j];
                    float hv = (1.0f - zv) * nn + zv * hp[n * 4 + j];
                    hout[((size_t)(tile * 16 + row) * NAGENT + a) * HID + col] = hv;
                    *(short*)(zb + row * 128 + ((col * 2) ^ ((row & 7) << 4))) = f2bf(hv);
                }
        }
    }

    // ---- fc2: q = h_new @ W2^T + b2 ----
    {
        float bq = b2[a * NACT + lr];
        f32x4 q = (f32x4){bq, bq, bq, bq};
        bf16x8 ha0 = *(const bf16x8*)(zb + lr * 128 + ((0 * 64 + lk * 16) ^ ((lr & 7) << 4)));
        bf16x8 ha1 = *(const bf16x8*)(zb + lr * 128 + ((1 * 64 + lk * 16) ^ ((lr & 7) << 4)));
        bf16x8 w2f0 = *(const bf16x8*)(wsA + 32768 + (0 * 64 + lane) * 8);
        bf16x8 w2f1 = *(const bf16x8*)(wsA + 32768 + (1 * 64 + lane) * 8);
        q = __builtin_amdgcn_mfma_f32_16x16x32_bf16(ha0, w2f0, q, 0, 0, 0);
        q = __builtin_amdgcn_mfma_f32_16x16x32_bf16(ha1, w2f1, q, 0, 0, 0);
        #pragma unroll
        for (int j = 0; j < 4; ++j)
            qout[((size_t)(tile * 16 + lk * 4 + j) * NAGENT + a) * NACT + lr] = q[j];
    }
}

extern "C" void kernel_launch(void* const* d_in, const int* in_sizes, int n_in,
                              void* d_out, int out_size, void* d_ws, size_t ws_size,
                              hipStream_t stream)
{
    const float* x   = (const float*)d_in[0];
    const float* hin = (const float*)d_in[1];
    const float* W1  = (const float*)d_in[2];
    const float* b1  = (const float*)d_in[3];
    const float* Wih = (const float*)d_in[4];
    const float* bih = (const float*)d_in[5];
    const float* Whh = (const float*)d_in[6];
    const float* bhh = (const float*)d_in[7];
    const float* W2  = (const float*)d_in[8];
    const float* b2  = (const float*)d_in[9];

    const int B = in_sizes[0] / (NAGENT * DIN);   // 16384

    float* qout = (float*)d_out;                              // [B*A, NACT]
    float* hout = (float*)d_out + (size_t)B * NAGENT * NACT;  // [B, A, H]

    short* wsp = (short*)d_ws;                                // 540,672 B packed

    conv_weights_packed<<<dim3(17, NAGENT), 256, 0, stream>>>(W1, Wih, Whh, W2, wsp);

    dim3 grid(B / 64, NAGENT);
    rnn_main<<<grid, 256, 0, stream>>>(x, hin, b1, bih, bhh, b2, wsp, qout, hout);
}

// Round 9
// 61.887 us; speedup vs baseline: 1.2218x; 1.2218x over previous
//
#include <hip/hip_runtime.h>
#include <hip/hip_bf16.h>
#include <cstddef>

#define NAGENT 8
#define DIN    128
#define HID    64
#define NACT   16

typedef __attribute__((ext_vector_type(8))) short bf16x8;
typedef __attribute__((ext_vector_type(4))) float f32x4;

__device__ __forceinline__ short f2bf(float f) {
    __hip_bfloat16 h = __float2bfloat16(f);      // RNE; pairs pack to v_cvt_pk_bf16_f32
    union { __hip_bfloat16 h; short s; } u; u.h = h;
    return u.s;
}
__device__ __forceinline__ float sigmoid_f(float v) { return 1.0f / (1.0f + __expf(-v)); }
__device__ __forceinline__ float tanh_f(float v) {
    v = fminf(fmaxf(v, -15.0f), 15.0f);
    float e = __expf(2.0f * v);
    return (e - 1.0f) / (e + 1.0f);
}
__device__ __forceinline__ bf16x8 cvt8pair(float4 v0, float4 v1) {
    bf16x8 r;
    r[0] = f2bf(v0.x); r[1] = f2bf(v0.y); r[2] = f2bf(v0.z); r[3] = f2bf(v0.w);
    r[4] = f2bf(v1.x); r[5] = f2bf(v1.y); r[6] = f2bf(v1.z); r[7] = f2bf(v1.w);
    return r;
}
__device__ __forceinline__ void gload_lds16(const void* g, void* l) {
    __builtin_amdgcn_global_load_lds(
        (const __attribute__((address_space(1))) unsigned int*)g,
        (__attribute__((address_space(3))) unsigned int*)l, 16, 0, 0);
}

// ---------------- weight fp32 -> bf16 fragment-major packing ----------------
// Per-agent packed layout (shorts), base a*33792:
//   W1  chunks c in [0,1024):    c = (n*4+k)*64 + lane      -> W1[a][n*16+lr][k*32+lk*8 ..+8]
//   Wih chunks c in [1024,2560): c-1024 = ((g*4+n)*2+kk)*64+lane -> Wih[a][g*64+n*16+lr][kk*32+lk*8..]
//   Whh chunks c in [2560,4096): same with Whh
//   W2  chunks c in [4096,4224): c-4096 = kk*64+lane        -> W2[a][lr][kk*32+lk*8..]
extern "C" __global__ void __launch_bounds__(256)
conv_weights_packed(const float* __restrict__ W1, const float* __restrict__ Wih,
                    const float* __restrict__ Whh, const float* __restrict__ W2,
                    short* __restrict__ ws)
{
    const int a = blockIdx.y;
    const int c = blockIdx.x * 256 + threadIdx.x;
    if (c >= 4224) return;
    const int lane = c & 63, lr = lane & 15, lk = lane >> 4;
    const float* src;
    if (c < 1024) {
        int n = c >> 8, k = (c >> 6) & 3;
        src = W1 + a * 8192 + (n * 16 + lr) * 128 + k * 32 + lk * 8;
    } else if (c < 2560) {
        int idx = (c - 1024) >> 6;
        int g = idx >> 3, n = (idx >> 1) & 3, kk = idx & 1;
        src = Wih + a * 12288 + (g * 64 + n * 16 + lr) * 64 + kk * 32 + lk * 8;
    } else if (c < 4096) {
        int idx = (c - 2560) >> 6;
        int g = idx >> 3, n = (idx >> 1) & 3, kk = idx & 1;
        src = Whh + a * 12288 + (g * 64 + n * 16 + lr) * 64 + kk * 32 + lk * 8;
    } else {
        int kk = (c - 4096) >> 6;
        src = W2 + a * 1024 + lr * 64 + kk * 32 + lk * 8;
    }
    float4 v0 = ((const float4*)src)[0];
    float4 v1 = ((const float4*)src)[1];
    bf16x8 o = cvt8pair(v0, v1);
    *(bf16x8*)(ws + (size_t)a * 33792 + (size_t)c * 8) = o;
}

// ---------------- main fused kernel ----------------
// grid (B/64, A) = 2048 blocks, 256 threads (4 waves), ONE 16-row tile/wave.
// __launch_bounds__(256, 2): empirically the ONLY spelling yielding 128 VGPRs
// (allocator lands one tier tighter than declared: (256,4)/big blocks -> 64
// VGPR + spills; see r4-r8). Lean body (no prefetch arrays, per-gate
// accumulator scoping) fits ~110 live regs -> zero spill at 128.
// LDS = Whh staged (24KB, on the latency-critical path: ds_read 120cy vs L2
// 200cy) + 4 x 2KB transpose = 32KB -> co-residency VGPR-bound at 4 blocks/CU
// = 16 waves/CU = 4 waves/SIMD. W1/Wih/W2 stream from packed d_ws (1KB
// contiguous wave bursts, L2-resident).
extern "C" __global__ void __launch_bounds__(256, 2)
rnn_main(const float* __restrict__ x,     // [B*A, D]
         const float* __restrict__ hin,   // [B, A, H]
         const float* __restrict__ b1, const float* __restrict__ bih,
         const float* __restrict__ bhh, const float* __restrict__ b2,
         const short* __restrict__ wsp,   // packed bf16 weights
         float* __restrict__ qout,        // [B*A, NACT]
         float* __restrict__ hout)        // [B, A, H]
{
    const int a    = blockIdx.y;
    const int t    = threadIdx.x;
    const int wid  = t >> 6;              // 0..3
    const int lane = t & 63;
    const int lr   = lane & 15;
    const int lk   = lane >> 4;

    __shared__ short whlds[12288];        // 24 KB Whh fragments
    __shared__ short zs[4 * 1024];        // 4 per-wave 2KB transpose buffers
    char* zb = (char*)(zs + wid * 1024);

    const short* wsA = wsp + (size_t)a * 33792;
    const int tile = blockIdx.x * 4 + wid;
    const int arow = tile * 16 + lr;

    // ---- stage Whh: 24 rounds x 1KB, split across 4 waves ----
    for (int r = wid; r < 24; r += 4)
        gload_lds16(wsA + 20480 + r * 512 + lane * 8, whlds + r * 512);

    // ---- x / h rows -> bf16 fragments (the only cold HBM loads) ----
    const float* xrow = x + ((size_t)arow * NAGENT + a) * DIN + lk * 8;
    const float* hrow = hin + ((size_t)arow * NAGENT + a) * HID + lk * 8;
    bf16x8 xf[4], hf[2];
    #pragma unroll
    for (int k = 0; k < 4; ++k)
        xf[k] = cvt8pair(*(const float4*)(xrow + k * 32),
                         *(const float4*)(xrow + k * 32 + 4));
    #pragma unroll
    for (int kk = 0; kk < 2; ++kk)
        hf[kk] = cvt8pair(*(const float4*)(hrow + kk * 32),
                          *(const float4*)(hrow + kk * 32 + 4));

    __syncthreads();   // Whh staged

    // ---- fc1: z1 = relu(x @ W1^T + b1), W1 fragments from L2 ----
    {
        f32x4 acc1[4];
        #pragma unroll
        for (int n = 0; n < 4; ++n) {
            float bv = b1[a * HID + n * 16 + lr];
            acc1[n] = (f32x4){bv, bv, bv, bv};
        }
        #pragma unroll
        for (int k = 0; k < 4; ++k)
            #pragma unroll
            for (int n = 0; n < 4; ++n) {
                bf16x8 wb = *(const bf16x8*)(wsA + ((n * 4 + k) * 64 + lane) * 8);
                acc1[n] = __builtin_amdgcn_mfma_f32_16x16x32_bf16(xf[k], wb, acc1[n], 0, 0, 0);
            }
        #pragma unroll
        for (int n = 0; n < 4; ++n)
            #pragma unroll
            for (int j = 0; j < 4; ++j) {
                int row = lk * 4 + j, col = n * 16 + lr;
                *(short*)(zb + row * 128 + ((col * 2) ^ ((row & 7) << 4))) =
                    f2bf(fmaxf(acc1[n][j], 0.0f));
            }
    }

    // ---- z1 back as A-fragments (round trip covered by gate-0 h-MFMAs) ----
    bf16x8 za0 = *(const bf16x8*)(zb + lr * 128 + ((0 * 64 + lk * 16) ^ ((lr & 7) << 4)));
    bf16x8 za1 = *(const bf16x8*)(zb + lr * 128 + ((1 * 64 + lk * 16) ^ ((lr & 7) << 4)));

    float rg[16], zg[16];
    float hp[16];

    #pragma unroll
    for (int g = 0; g < 3; ++g) {
        // h-path accumulators for THIS gate only (Whh from LDS)
        f32x4 aH[4];
        #pragma unroll
        for (int n = 0; n < 4; ++n) {
            float bh = bhh[a * 3 * HID + g * HID + n * 16 + lr];
            aH[n] = (f32x4){bh, bh, bh, bh};
        }
        #pragma unroll
        for (int kk = 0; kk < 2; ++kk)
            #pragma unroll
            for (int n = 0; n < 4; ++n) {
                bf16x8 wh = *(const bf16x8*)(whlds +
                              (((g * 4 + n) * 2 + kk) * 64 + lane) * 8);
                aH[n] = __builtin_amdgcn_mfma_f32_16x16x32_bf16(hf[kk], wh, aH[n], 0, 0, 0);
            }

        f32x4 aI[4];
        #pragma unroll
        for (int n = 0; n < 4; ++n) {
            float bi = bih[a * 3 * HID + g * HID + n * 16 + lr];
            aI[n] = (f32x4){bi, bi, bi, bi};
        }
        #pragma unroll
        for (int n = 0; n < 4; ++n) {
            bf16x8 wi0 = *(const bf16x8*)(wsA + 8192 +
                          (((g * 4 + n) * 2 + 0) * 64 + lane) * 8);
            bf16x8 wi1 = *(const bf16x8*)(wsA + 8192 +
                          (((g * 4 + n) * 2 + 1) * 64 + lane) * 8);
            aI[n] = __builtin_amdgcn_mfma_f32_16x16x32_bf16(za0, wi0, aI[n], 0, 0, 0);
            aI[n] = __builtin_amdgcn_mfma_f32_16x16x32_bf16(za1, wi1, aI[n], 0, 0, 0);
        }

        if (g == 0) {
            #pragma unroll
            for (int n = 0; n < 4; ++n)
                #pragma unroll
                for (int j = 0; j < 4; ++j)
                    rg[n * 4 + j] = sigmoid_f(aI[n][j] + aH[n][j]);
            // issue hp loads now: L1 hits (same lines as hrow), consumed in g==2
            #pragma unroll
            for (int n = 0; n < 4; ++n)
                #pragma unroll
                for (int j = 0; j < 4; ++j)
                    hp[n * 4 + j] =
                        hin[((size_t)(tile * 16 + lk * 4 + j) * NAGENT + a) * HID + n * 16 + lr];
        } else if (g == 1) {
            #pragma unroll
            for (int n = 0; n < 4; ++n)
                #pragma unroll
                for (int j = 0; j < 4; ++j)
                    zg[n * 4 + j] = sigmoid_f(aI[n][j] + aH[n][j]);
        } else {
            #pragma unroll
            for (int n = 0; n < 4; ++n)
                #pragma unroll
                for (int j = 0; j < 4; ++j) {
                    int row = lk * 4 + j, col = n * 16 + lr;
                    float nn = tanh_f(aI[n][j] + rg[n * 4 + j] * aH[n][j]);
                    float zv = zg[n * 4 + j];
                    float hv = (1.0f - zv) * nn + zv * hp[n * 4 + j];
                    hout[((size_t)(tile * 16 + row) * NAGENT + a) * HID + col] = hv;
                    *(short*)(zb + row * 128 + ((col * 2) ^ ((row & 7) << 4))) = f2bf(hv);
                }
        }
    }

    // ---- fc2: q = h_new @ W2^T + b2 ----
    {
        float bq = b2[a * NACT + lr];
        f32x4 q = (f32x4){bq, bq, bq, bq};
        bf16x8 ha0 = *(const bf16x8*)(zb + lr * 128 + ((0 * 64 + lk * 16) ^ ((lr & 7) << 4)));
        bf16x8 ha1 = *(const bf16x8*)(zb + lr * 128 + ((1 * 64 + lk * 16) ^ ((lr & 7) << 4)));
        bf16x8 w2f0 = *(const bf16x8*)(wsA + 32768 + (0 * 64 + lane) * 8);
        bf16x8 w2f1 = *(const bf16x8*)(wsA + 32768 + (1 * 64 + lane) * 8);
        q = __builtin_amdgcn_mfma_f32_16x16x32_bf16(ha0, w2f0, q, 0, 0, 0);
        q = __builtin_amdgcn_mfma_f32_16x16x32_bf16(ha1, w2f1, q, 0, 0, 0);
        #pragma unroll
        for (int j = 0; j < 4; ++j)
            qout[((size_t)(tile * 16 + lk * 4 + j) * NAGENT + a) * NACT + lr] = q[j];
    }
}

extern "C" void kernel_launch(void* const* d_in, const int* in_sizes, int n_in,
                              void* d_out, int out_size, void* d_ws, size_t ws_size,
                              hipStream_t stream)
{
    const float* x   = (const float*)d_in[0];
    const float* hin = (const float*)d_in[1];
    const float* W1  = (const float*)d_in[2];
    const float* b1  = (const float*)d_in[3];
    const float* Wih = (const float*)d_in[4];
    const float* bih = (const float*)d_in[5];
    const float* Whh = (const float*)d_in[6];
    const float* bhh = (const float*)d_in[7];
    const float* W2  = (const float*)d_in[8];
    const float* b2  = (const float*)d_in[9];

    const int B = in_sizes[0] / (NAGENT * DIN);   // 16384

    float* qout = (float*)d_out;                              // [B*A, NACT]
    float* hout = (float*)d_out + (size_t)B * NAGENT * NACT;  // [B, A, H]

    short* wsp = (short*)d_ws;                                // 540,672 B packed

    conv_weights_packed<<<dim3(17, NAGENT), 256, 0, stream>>>(W1, Wih, Whh, W2, wsp);

    dim3 grid(B / 64, NAGENT);
    rnn_main<<<grid, 256, 0, stream>>>(x, hin, b1, bih, bhh, b2, wsp, qout, hout);
}

// Round 10
// 48.522 us; speedup vs baseline: 1.5583x; 1.2754x over previous
//
#include <hip/hip_runtime.h>
#include <hip/hip_bf16.h>
#include <cstddef>

#define NAGENT 8
#define DIN    128
#define HID    64
#define NACT   16

typedef __attribute__((ext_vector_type(8))) short bf16x8;
typedef __attribute__((ext_vector_type(4))) float f32x4;

__device__ __forceinline__ short f2bf(float f) {
    __hip_bfloat16 h = __float2bfloat16(f);      // RNE; pairs pack to v_cvt_pk_bf16_f32
    union { __hip_bfloat16 h; short s; } u; u.h = h;
    return u.s;
}
__device__ __forceinline__ float sigmoid_f(float v) { return 1.0f / (1.0f + __expf(-v)); }
__device__ __forceinline__ float tanh_f(float v) {
    v = fminf(fmaxf(v, -15.0f), 15.0f);
    float e = __expf(2.0f * v);
    return (e - 1.0f) / (e + 1.0f);
}
__device__ __forceinline__ bf16x8 cvt8pair(float4 v0, float4 v1) {
    bf16x8 r;
    r[0] = f2bf(v0.x); r[1] = f2bf(v0.y); r[2] = f2bf(v0.z); r[3] = f2bf(v0.w);
    r[4] = f2bf(v1.x); r[5] = f2bf(v1.y); r[6] = f2bf(v1.z); r[7] = f2bf(v1.w);
    return r;
}

// ---------------- weight fp32 -> bf16 fragment-major packing ----------------
// Per-agent packed layout (shorts), base a*33792:
//   W1  chunks c in [0,1024):    c = (n*4+k)*64 + lane      -> W1[a][n*16+lr][k*32+lk*8 ..+8]
//   Wih chunks c in [1024,2560): c-1024 = ((g*4+n)*2+kk)*64+lane -> Wih[a][g*64+n*16+lr][kk*32+lk*8..]
//   Whh chunks c in [2560,4096): same with Whh
//   W2  chunks c in [4096,4224): c-4096 = kk*64+lane        -> W2[a][lr][kk*32+lk*8..]
extern "C" __global__ void __launch_bounds__(256)
conv_weights_packed(const float* __restrict__ W1, const float* __restrict__ Wih,
                    const float* __restrict__ Whh, const float* __restrict__ W2,
                    short* __restrict__ ws)
{
    const int a = blockIdx.y;
    const int c = blockIdx.x * 256 + threadIdx.x;
    if (c >= 4224) return;
    const int lane = c & 63, lr = lane & 15, lk = lane >> 4;
    const float* src;
    if (c < 1024) {
        int n = c >> 8, k = (c >> 6) & 3;
        src = W1 + a * 8192 + (n * 16 + lr) * 128 + k * 32 + lk * 8;
    } else if (c < 2560) {
        int idx = (c - 1024) >> 6;
        int g = idx >> 3, n = (idx >> 1) & 3, kk = idx & 1;
        src = Wih + a * 12288 + (g * 64 + n * 16 + lr) * 64 + kk * 32 + lk * 8;
    } else if (c < 4096) {
        int idx = (c - 2560) >> 6;
        int g = idx >> 3, n = (idx >> 1) & 3, kk = idx & 1;
        src = Whh + a * 12288 + (g * 64 + n * 16 + lr) * 64 + kk * 32 + lk * 8;
    } else {
        int kk = (c - 4096) >> 6;
        src = W2 + a * 1024 + lr * 64 + kk * 32 + lk * 8;
    }
    float4 v0 = ((const float4*)src)[0];
    float4 v1 = ((const float4*)src)[1];
    bf16x8 o = cvt8pair(v0, v1);
    *(bf16x8*)(ws + (size_t)a * 33792 + (size_t)c * 8) = o;
}

// ---------------- main fused kernel ----------------
// grid (B/64, A) = 2048 blocks, 256 threads (4 waves), ONE 16-row tile/wave.
// TARGET: the 64-VGPR occupancy tier (8 waves/SIMD = 32 waves/CU).
//  - __launch_bounds__(256,4) pins the allocator to 64 VGPRs (r8 evidence).
//  - column-block-wise gates: no rg/zg/hp arrays (r9's 48 live regs gone);
//    per 16-col block compute all 3 gates' aI/aH transiently, then r/z/n/h_new
//    inline and store. #pragma unroll 1 keeps fragment batching bounded.
//  - no weight LDS staging, no barriers: all weights stream from packed d_ws
//    (contiguous 1KB wave bursts, L2-resident). LDS = 4x2KB transpose only
//    -> co-residency VGPR-bound at 8 blocks/CU.
extern "C" __global__ void __launch_bounds__(256, 4)
rnn_main(const float* __restrict__ x,     // [B*A, D]
         const float* __restrict__ hin,   // [B, A, H]
         const float* __restrict__ b1, const float* __restrict__ bih,
         const float* __restrict__ bhh, const float* __restrict__ b2,
         const short* __restrict__ wsp,   // packed bf16 weights
         float* __restrict__ qout,        // [B*A, NACT]
         float* __restrict__ hout)        // [B, A, H]
{
    const int a    = blockIdx.y;
    const int t    = threadIdx.x;
    const int wid  = t >> 6;              // 0..3
    const int lane = t & 63;
    const int lr   = lane & 15;
    const int lk   = lane >> 4;

    __shared__ short zs[4 * 1024];        // 4 per-wave 2KB transpose buffers
    char* zb = (char*)(zs + wid * 1024);

    const short* wsA = wsp + (size_t)a * 33792;
    const int tile = blockIdx.x * 4 + wid;
    const int arow = tile * 16 + lr;

    // ---- x / h rows -> bf16 fragments ----
    const float* xrow = x + ((size_t)arow * NAGENT + a) * DIN + lk * 8;
    const float* hrow = hin + ((size_t)arow * NAGENT + a) * HID + lk * 8;
    bf16x8 hf0 = cvt8pair(*(const float4*)(hrow),      *(const float4*)(hrow + 4));
    bf16x8 hf1 = cvt8pair(*(const float4*)(hrow + 32), *(const float4*)(hrow + 36));

    // ---- fc1: z1 = relu(x @ W1^T + b1) ----
    {
        f32x4 acc1[4];
        #pragma unroll
        for (int n = 0; n < 4; ++n) {
            float bv = b1[a * HID + n * 16 + lr];
            acc1[n] = (f32x4){bv, bv, bv, bv};
        }
        #pragma unroll
        for (int k = 0; k < 4; ++k) {
            bf16x8 xk = cvt8pair(*(const float4*)(xrow + k * 32),
                                 *(const float4*)(xrow + k * 32 + 4));
            #pragma unroll
            for (int n = 0; n < 4; ++n) {
                bf16x8 wb = *(const bf16x8*)(wsA + ((n * 4 + k) * 64 + lane) * 8);
                acc1[n] = __builtin_amdgcn_mfma_f32_16x16x32_bf16(xk, wb, acc1[n], 0, 0, 0);
            }
        }
        #pragma unroll
        for (int n = 0; n < 4; ++n)
            #pragma unroll
            for (int j = 0; j < 4; ++j) {
                int row = lk * 4 + j, col = n * 16 + lr;
                *(short*)(zb + row * 128 + ((col * 2) ^ ((row & 7) << 4))) =
                    f2bf(fmaxf(acc1[n][j], 0.0f));
            }
    }

    // ---- z1 back as A-fragments ----
    bf16x8 za0 = *(const bf16x8*)(zb + lr * 128 + ((0 * 64 + lk * 16) ^ ((lr & 7) << 4)));
    bf16x8 za1 = *(const bf16x8*)(zb + lr * 128 + ((1 * 64 + lk * 16) ^ ((lr & 7) << 4)));

    // ---- GRU gates, column-block-wise (16 cols at a time) ----
    #pragma unroll 1
    for (int n = 0; n < 4; ++n) {
        // h-path accumulators, all 3 gates for THIS col-block
        float bhr = bhh[a * 192 +   0 + n * 16 + lr];
        float bhz = bhh[a * 192 +  64 + n * 16 + lr];
        float bhn = bhh[a * 192 + 128 + n * 16 + lr];
        f32x4 aHr = (f32x4){bhr, bhr, bhr, bhr};
        f32x4 aHz = (f32x4){bhz, bhz, bhz, bhz};
        f32x4 aHn = (f32x4){bhn, bhn, bhn, bhn};
        #pragma unroll
        for (int kk = 0; kk < 2; ++kk) {
            bf16x8 hfk = kk ? hf1 : hf0;
            bf16x8 whr = *(const bf16x8*)(wsA + 20480 + (((0 * 4 + n) * 2 + kk) * 64 + lane) * 8);
            bf16x8 whz = *(const bf16x8*)(wsA + 20480 + (((1 * 4 + n) * 2 + kk) * 64 + lane) * 8);
            bf16x8 whn = *(const bf16x8*)(wsA + 20480 + (((2 * 4 + n) * 2 + kk) * 64 + lane) * 8);
            aHr = __builtin_amdgcn_mfma_f32_16x16x32_bf16(hfk, whr, aHr, 0, 0, 0);
            aHz = __builtin_amdgcn_mfma_f32_16x16x32_bf16(hfk, whz, aHz, 0, 0, 0);
            aHn = __builtin_amdgcn_mfma_f32_16x16x32_bf16(hfk, whn, aHn, 0, 0, 0);
        }

        // i-path accumulators, all 3 gates
        float bir = bih[a * 192 +   0 + n * 16 + lr];
        float biz = bih[a * 192 +  64 + n * 16 + lr];
        float bin_ = bih[a * 192 + 128 + n * 16 + lr];
        f32x4 aIr = (f32x4){bir, bir, bir, bir};
        f32x4 aIz = (f32x4){biz, biz, biz, biz};
        f32x4 aIn = (f32x4){bin_, bin_, bin_, bin_};
        #pragma unroll
        for (int kk = 0; kk < 2; ++kk) {
            bf16x8 zak = kk ? za1 : za0;
            bf16x8 wir = *(const bf16x8*)(wsA + 8192 + (((0 * 4 + n) * 2 + kk) * 64 + lane) * 8);
            bf16x8 wiz = *(const bf16x8*)(wsA + 8192 + (((1 * 4 + n) * 2 + kk) * 64 + lane) * 8);
            bf16x8 win = *(const bf16x8*)(wsA + 8192 + (((2 * 4 + n) * 2 + kk) * 64 + lane) * 8);
            aIr = __builtin_amdgcn_mfma_f32_16x16x32_bf16(zak, wir, aIr, 0, 0, 0);
            aIz = __builtin_amdgcn_mfma_f32_16x16x32_bf16(zak, wiz, aIz, 0, 0, 0);
            aIn = __builtin_amdgcn_mfma_f32_16x16x32_bf16(zak, win, aIn, 0, 0, 0);
        }

        // elementwise + stores for this col-block
        #pragma unroll
        for (int j = 0; j < 4; ++j) {
            int row = lk * 4 + j, col = n * 16 + lr;
            float hp = hin[((size_t)(tile * 16 + row) * NAGENT + a) * HID + col];
            float r  = sigmoid_f(aIr[j] + aHr[j]);
            float zv = sigmoid_f(aIz[j] + aHz[j]);
            float nn = tanh_f(aIn[j] + r * aHn[j]);
            float hv = (1.0f - zv) * nn + zv * hp;
            hout[((size_t)(tile * 16 + row) * NAGENT + a) * HID + col] = hv;
            *(short*)(zb + row * 128 + ((col * 2) ^ ((row & 7) << 4))) = f2bf(hv);
        }
    }

    // ---- fc2: q = h_new @ W2^T + b2 ----
    {
        float bq = b2[a * NACT + lr];
        f32x4 q = (f32x4){bq, bq, bq, bq};
        bf16x8 ha0 = *(const bf16x8*)(zb + lr * 128 + ((0 * 64 + lk * 16) ^ ((lr & 7) << 4)));
        bf16x8 ha1 = *(const bf16x8*)(zb + lr * 128 + ((1 * 64 + lk * 16) ^ ((lr & 7) << 4)));
        bf16x8 w2f0 = *(const bf16x8*)(wsA + 32768 + (0 * 64 + lane) * 8);
        bf16x8 w2f1 = *(const bf16x8*)(wsA + 32768 + (1 * 64 + lane) * 8);
        q = __builtin_amdgcn_mfma_f32_16x16x32_bf16(ha0, w2f0, q, 0, 0, 0);
        q = __builtin_amdgcn_mfma_f32_16x16x32_bf16(ha1, w2f1, q, 0, 0, 0);
        #pragma unroll
        for (int j = 0; j < 4; ++j)
            qout[((size_t)(tile * 16 + lk * 4 + j) * NAGENT + a) * NACT + lr] = q[j];
    }
}

extern "C" void kernel_launch(void* const* d_in, const int* in_sizes, int n_in,
                              void* d_out, int out_size, void* d_ws, size_t ws_size,
                              hipStream_t stream)
{
    const float* x   = (const float*)d_in[0];
    const float* hin = (const float*)d_in[1];
    const float* W1  = (const float*)d_in[2];
    const float* b1  = (const float*)d_in[3];
    const float* Wih = (const float*)d_in[4];
    const float* bih = (const float*)d_in[5];
    const float* Whh = (const float*)d_in[6];
    const float* bhh = (const float*)d_in[7];
    const float* W2  = (const float*)d_in[8];
    const float* b2  = (const float*)d_in[9];

    const int B = in_sizes[0] / (NAGENT * DIN);   // 16384

    float* qout = (float*)d_out;                              // [B*A, NACT]
    float* hout = (float*)d_out + (size_t)B * NAGENT * NACT;  // [B, A, H]

    short* wsp = (short*)d_ws;                                // 540,672 B packed

    conv_weights_packed<<<dim3(17, NAGENT), 256, 0, stream>>>(W1, Wih, Whh, W2, wsp);

    dim3 grid(B / 64, NAGENT);
    rnn_main<<<grid, 256, 0, stream>>>(x, hin, b1, bih, bhh, b2, wsp, qout, hout);
}